// Round 6
// baseline (223.852 us; speedup 1.0000x reference)
//
#include <hip/hip_runtime.h>
#include <hip/hip_bf16.h>
#include <stdint.h>

// ConvMoE: B=32, C=384, H=W=28, E=4, HID=384, K=2. N tokens = 25088.
// Fused: per 64-token stripe: GEMM1 (K=384) -> coef*relu -> S(LDS) ->
// GEMM2 accumulate (K=1536) -> out. Weights pre-packed per-lane (W1f/W2f).
#define B_DIM 32
#define C_DIM 384
#define HW_DIM 784
#define E_DIM 4
#define HID_DIM 384
#define NTOK (B_DIM * HW_DIM)   // 25088
#define NH (E_DIM * HID_DIM)    // 1536
#define NPANEL 12               // 1536 / 128
#define WSZ 589824              // NH*C_DIM = C_DIM*NH

using short8 = __attribute__((ext_vector_type(8))) short;
using f32x4  = __attribute__((ext_vector_type(4))) float;
typedef unsigned short ushort_t;

__device__ __forceinline__ ushort_t f2bf(float f) {
  __hip_bfloat16 h = __float2bfloat16(f);
  return __builtin_bit_cast(ushort_t, h);
}

__device__ __forceinline__ void gload_lds16(const void* g, void* l) {
  __builtin_amdgcn_global_load_lds(
      (const __attribute__((address_space(1))) unsigned int*)g,
      (__attribute__((address_space(3))) unsigned int*)l, 16, 0, 0);
}

// ---- kernel 1: pack weights into per-lane MFMA fragment order --------------
// W1f[n1][wsn][ni(2)][ks(12)][lane(64)][t(8)]  (frag: col=lane&15, k=(lane>>4)*8+t)
// W2f[n1][wso][ni(6)][ks(4)][lane(64)][t(8)]
__global__ __launch_bounds__(256) void prep_kernel(
    const float* __restrict__ w1, const float* __restrict__ w2,
    ushort_t* __restrict__ W1f, ushort_t* __restrict__ W2f,
    unsigned int* __restrict__ present) {
  int i = blockIdx.x * 256 + threadIdx.x;
  if (i == 0) *present = 0u;
  if (i >= WSZ) return;
  {
    int r = i;
    const int n1 = r / 49152; r -= n1 * 49152;
    const int wsn = r / 12288; r -= wsn * 12288;
    const int ni = r / 6144;  r -= ni * 6144;
    const int ks = r / 512;   r -= ks * 512;
    const int ln = r / 8;     const int t = r - ln * 8;
    const int nrow = n1 * 128 + wsn * 32 + ni * 16 + (ln & 15);
    const int c = ks * 32 + (ln >> 4) * 8 + t;
    W1f[i] = f2bf(w1[(size_t)nrow * C_DIM + c]);   // w1 flat [e*HID+d][c]
  }
  {
    int r = i;
    const int n1 = r / 49152; r -= n1 * 49152;
    const int wso = r / 12288; r -= wso * 12288;
    const int ni = r / 2048;  r -= ni * 2048;
    const int ks = r / 512;   r -= ks * 512;
    const int ln = r / 8;     const int t = r - ln * 8;
    const int o = wso * 96 + ni * 16 + (ln & 15);
    const int kg = n1 * 128 + ks * 32 + (ln >> 4) * 8 + t;
    const int e = kg / HID_DIM;
    const int d = kg - e * HID_DIM;
    W2f[i] = f2bf(w2[((size_t)e * C_DIM + o) * HID_DIM + d]);  // w2 [E][C][HID]
  }
}

// ---- kernel 2: gate + softmax + top2 + x -> bf16 [N][C] --------------------
__global__ __launch_bounds__(256) void gate_kernel(
    const float* __restrict__ x, const float* __restrict__ gw,
    const float* __restrict__ gb, ushort_t* __restrict__ xb,
    float* __restrict__ topw, unsigned int* __restrict__ present) {
  __shared__ __align__(16) ushort_t lxs[64][392];
  __shared__ float pscore[4][64][4];
  __shared__ unsigned int pmask;
  const int b = blockIdx.x;
  const int p0 = blockIdx.y * 64;
  const int cnt = min(64, HW_DIM - p0);
  const int tid = threadIdx.x;
  const int cg = tid >> 6, tl = tid & 63;
  if (tid == 0) pmask = 0u;
  float a0 = 0.f, a1 = 0.f, a2 = 0.f, a3 = 0.f;
  const bool valid = tl < cnt;
  if (valid) {
    const float* xp = x + (size_t)b * C_DIM * HW_DIM + p0 + tl;
    for (int c = cg; c < C_DIM; c += 4) {
      const float v = xp[(size_t)c * HW_DIM];
      lxs[tl][c] = f2bf(v);
      const float4 g = *(const float4*)&gw[c * 4];
      a0 += v * g.x; a1 += v * g.y; a2 += v * g.z; a3 += v * g.w;
    }
  }
  pscore[cg][tl][0] = a0; pscore[cg][tl][1] = a1;
  pscore[cg][tl][2] = a2; pscore[cg][tl][3] = a3;
  __syncthreads();
  if (cg == 0 && valid) {
    float z[4];
#pragma unroll
    for (int e = 0; e < 4; e++)
      z[e] = pscore[0][tl][e] + pscore[1][tl][e] + pscore[2][tl][e] +
             pscore[3][tl][e] + gb[e];
    const float mx = fmaxf(fmaxf(z[0], z[1]), fmaxf(z[2], z[3]));
    float s[4]; float sum = 0.f;
#pragma unroll
    for (int e = 0; e < 4; e++) { s[e] = __expf(z[e] - mx); sum += s[e]; }
    const float inv = 1.f / sum;
#pragma unroll
    for (int e = 0; e < 4; e++) s[e] *= inv;
    int e0 = 0; float v0 = s[0];
#pragma unroll
    for (int e = 1; e < 4; e++) if (s[e] > v0) { v0 = s[e]; e0 = e; }
    int e1 = -1; float v1 = -1.f;
#pragma unroll
    for (int e = 0; e < 4; e++) if (e != e0 && s[e] > v1) { v1 = s[e]; e1 = e; }
    const float r = __expf(v1 - v0);
    const float w0 = 1.f / (1.f + r);
    const int m = b * HW_DIM + p0 + tl;
    topw[m * 2] = w0;
    topw[m * 2 + 1] = 1.f - w0;
    atomicOr(&pmask, (1u << e0) | (1u << (4 + e1)));
  }
  __syncthreads();
  if (tid == 0) atomicOr(present, pmask);
  const int nchunk = cnt * 48;
  for (int ci = tid; ci < nchunk; ci += 256) {
    const int row = ci / 48, c8 = ci - row * 48;
    short8 v = *(const short8*)&lxs[row][c8 * 8];
    *(short8*)&xb[(size_t)(b * HW_DIM + p0 + row) * C_DIM + c8 * 8] = v;
  }
}

// ---- kernel 3: fused MoE MLP over a 64-token stripe ------------------------
// 512 thr = 8 waves as (wsm 0..1) x (wsn 0..3). LDS: x 48KB + S dbuf 32KB.
__global__ __launch_bounds__(512, 4) void moe_fused(
    const ushort_t* __restrict__ xb, const ushort_t* __restrict__ W1f,
    const ushort_t* __restrict__ W2f, const float* __restrict__ b1,
    const float* __restrict__ b2, const float* __restrict__ topw,
    const unsigned int* __restrict__ presentp, float* __restrict__ outp) {
  __shared__ __align__(16) ushort_t lds[(49152 + 2 * 16384) / 2];  // 80 KB
  char* const ldsb = (char*)lds;
  const int tid = threadIdx.x;
  const int lane = tid & 63;
  const int wid = tid >> 6;
  const int wsm = wid >> 2, wsn = wid & 3;
  const int m0 = blockIdx.x * 64;
  const int laneq = lane >> 4;           // k-group 0..3
  const int lanel = lane & 15;
  const int xsw = (lane & 7) << 4;       // XOR swizzle (rows == lane mod 8)

  // stage x stripe [64][384] bf16, XOR-swizzled via pre-swizzled global src
#pragma unroll
  for (int li = 0; li < 6; ++li) {
    const int P = (li * 512 + tid) * 16;
    const int row = P / 768, cb = P - row * 768;
    gload_lds16(&xb[(size_t)(m0 + row) * C_DIM + ((cb ^ ((row & 7) << 4)) >> 1)],
                ldsb + P);
  }
  asm volatile("s_waitcnt vmcnt(0)" ::: "memory");
  __syncthreads();

  const unsigned int pm = *presentp;
  f32x4 acc[2][6] = {};                  // out accum [mi][ni], 32x96 per wave
  // per-lane A-frag row bases (x and S share the row pattern)
  const int arow0 = wsm * 32 + lanel;    // + mi*16

#pragma unroll 2
  for (int n1 = 0; n1 < NPANEL; ++n1) {
    // ---------- GEMM1: S(32x32 per wave) = x @ W1panel^T ----------
    f32x4 accs[2][2] = {};
    const ushort_t* w1p = W1f + (size_t)(n1 * 4 + wsn) * 12288;
#pragma unroll
    for (int ks = 0; ks < 12; ++ks) {
      short8 xa[2], wb[2];
#pragma unroll
      for (int mi = 0; mi < 2; ++mi)
        xa[mi] = *(const short8*)(ldsb + (arow0 + mi * 16) * 768 +
                                  ((ks * 64 + laneq * 16) ^ xsw));
#pragma unroll
      for (int ni = 0; ni < 2; ++ni)
        wb[ni] = *(const short8*)&w1p[ni * 6144 + ks * 512 + lane * 8];
#pragma unroll
      for (int mi = 0; mi < 2; ++mi)
#pragma unroll
        for (int ni = 0; ni < 2; ++ni)
          accs[mi][ni] = __builtin_amdgcn_mfma_f32_16x16x32_bf16(
              xa[mi], wb[ni], accs[mi][ni], 0, 0, 0);
    }
    // ---------- S epilogue: coef * relu(accs + b1) -> S_lds ----------
    char* Sb = ldsb + 49152 + (n1 & 1) * 16384;
    const int e = n1 / 3;
    const float P0 = (float)((pm >> e) & 1u);
    const float P1 = (float)((pm >> (4 + e)) & 1u);
#pragma unroll
    for (int mi = 0; mi < 2; ++mi) {
      const int mrow = m0 + wsm * 32 + mi * 16 + laneq * 4;
      const float4 t0 = *(const float4*)&topw[mrow * 2];
      const float4 t1 = *(const float4*)&topw[mrow * 2 + 4];
      const float cj[4] = {P0 * t0.x + P1 * t0.y, P0 * t0.z + P1 * t0.w,
                           P0 * t1.x + P1 * t1.y, P0 * t1.z + P1 * t1.w};
#pragma unroll
      for (int ni = 0; ni < 2; ++ni) {
        const int col = wsn * 32 + ni * 16 + lanel;
        const float bvv = b1[n1 * 128 + col];
#pragma unroll
        for (int j = 0; j < 4; ++j) {
          const int rl = wsm * 32 + mi * 16 + laneq * 4 + j;
          const float v = fmaxf(accs[mi][ni][j] + bvv, 0.f) * cj[j];
          *(ushort_t*)(Sb + rl * 256 + ((col * 2) ^ ((rl & 7) << 4))) = f2bf(v);
        }
      }
    }
    __syncthreads();                      // S visible; prior S-buf reads done
    // ---------- GEMM2: acc(32x96 per wave) += S @ W2panel^T ----------
    const ushort_t* w2p = W2f + (size_t)(n1 * 4 + wsn) * 12288;
#pragma unroll
    for (int ks = 0; ks < 4; ++ks) {
      short8 sa[2];
#pragma unroll
      for (int mi = 0; mi < 2; ++mi)
        sa[mi] = *(const short8*)(Sb + (arow0 + mi * 16) * 256 +
                                  ((ks * 64 + laneq * 16) ^ xsw));
#pragma unroll
      for (int ni = 0; ni < 6; ++ni) {
        const short8 wv = *(const short8*)&w2p[ni * 2048 + ks * 512 + lane * 8];
#pragma unroll
        for (int mi = 0; mi < 2; ++mi)
          acc[mi][ni] = __builtin_amdgcn_mfma_f32_16x16x32_bf16(
              sa[mi], wv, acc[mi][ni], 0, 0, 0);
      }
    }
  }

  // ---------- out epilogue: + (tw0*B0 + tw1*B1), float4 along p ----------
  float B0[6], B1[6];
#pragma unroll
  for (int ni = 0; ni < 6; ++ni) {
    const int o = wsn * 96 + ni * 16 + lanel;
    float s0 = 0.f, s1 = 0.f;
#pragma unroll
    for (int e2 = 0; e2 < 4; ++e2) {
      const float bb = b2[e2 * C_DIM + o];
      s0 += (float)((pm >> e2) & 1u) * bb;
      s1 += (float)((pm >> (4 + e2)) & 1u) * bb;
    }
    B0[ni] = s0; B1[ni] = s1;
  }
#pragma unroll
  for (int mi = 0; mi < 2; ++mi) {
    const int mg = m0 + wsm * 32 + mi * 16 + laneq * 4;
    const float4 t0 = *(const float4*)&topw[mg * 2];
    const float4 t1 = *(const float4*)&topw[mg * 2 + 4];
    const int bb2 = mg / HW_DIM;
    const int p = mg - bb2 * HW_DIM;     // 4 consecutive p, same batch
#pragma unroll
    for (int ni = 0; ni < 6; ++ni) {
      const int o = wsn * 96 + ni * 16 + lanel;
      float4 v;
      v.x = acc[mi][ni][0] + t0.x * B0[ni] + t0.y * B1[ni];
      v.y = acc[mi][ni][1] + t0.z * B0[ni] + t0.w * B1[ni];
      v.z = acc[mi][ni][2] + t1.x * B0[ni] + t1.y * B1[ni];
      v.w = acc[mi][ni][3] + t1.z * B0[ni] + t1.w * B1[ni];
      *(float4*)&outp[((size_t)bb2 * C_DIM + o) * HW_DIM + p] = v;
    }
  }
}

extern "C" void kernel_launch(void* const* d_in, const int* in_sizes, int n_in,
                              void* d_out, int out_size, void* d_ws, size_t ws_size,
                              hipStream_t stream) {
  const float* x  = (const float*)d_in[0];
  const float* gw = (const float*)d_in[1];
  const float* gb = (const float*)d_in[2];
  const float* w1 = (const float*)d_in[3];
  const float* b1 = (const float*)d_in[4];
  const float* w2 = (const float*)d_in[5];
  const float* b2 = (const float*)d_in[6];
  float* out = (float*)d_out;

  char* ws = (char*)d_ws;
  ushort_t* xb = (ushort_t*)ws;   ws += (size_t)NTOK * C_DIM * 2;
  ushort_t* W1f = (ushort_t*)ws;  ws += (size_t)WSZ * 2;
  ushort_t* W2f = (ushort_t*)ws;  ws += (size_t)WSZ * 2;
  float* topw = (float*)ws;       ws += (size_t)NTOK * 2 * 4;
  unsigned int* present = (unsigned int*)ws;

  prep_kernel<<<dim3((WSZ + 255) / 256), dim3(256), 0, stream>>>(
      w1, w2, W1f, W2f, present);
  gate_kernel<<<dim3(B_DIM, 13), dim3(256), 0, stream>>>(
      x, gw, gb, xb, topw, present);
  moe_fused<<<dim3(NTOK / 64), dim3(512), 0, stream>>>(
      xb, W1f, W2f, b1, b2, topw, present, out);
}